// Round 4
// baseline (137.584 us; speedup 1.0000x reference)
//
#include <hip/hip_runtime.h>
#include <math.h>

#define HDIM 128

// ---------------------------------------------------------------------------
// Fused bounds + init + out-zero. segment_ids is sorted; starts[s] = first t
// with seg[t] >= s. Thread t covers (seg[t-1], seg[t]]; thread 0 covers
// [0, seg[0]]; thread T-1 covers trailing empty segments (seg[T-1], B] with T.
// ---------------------------------------------------------------------------
__global__ void seg_bounds_kernel(const int* __restrict__ seg,
                                  int* __restrict__ starts, int Tval, int Bval,
                                  float* __restrict__ out) {
    int t = blockIdx.x * blockDim.x + threadIdx.x;
    if (t >= Tval) return;
    int b = seg[t];
    int a = (t == 0) ? -1 : seg[t - 1];
    for (int s = a + 1; s <= b; ++s) starts[s] = t;
    if (t == Tval - 1)
        for (int s = b + 1; s <= Bval; ++s) starts[s] = Tval;
    if (t == 0) out[0] = 0.0f;
}

// ---------------------------------------------------------------------------
// Fused gather-mean + MLP + BCE, drain-tail version.
// R3 post-mortem: gather runs at the memory system's random-512B service
// rate (~4.5 TB/s), but OccupancyPercent 33% vs static 50% shows ~30% of
// wall time is the drain tail (1 wave/segment, segment length ~Poisson(100),
// max ~140). This version: TWO waves per segment (contiguous halves, same
// block), 2048 blocks x 4 waves = 8192 waves = 100% of wave slots, and the
// tail quantum halves. Unlike the failed R2 split: W_hid is K-SPLIT (each
// wave reads only its 32 KB half => per-segment W traffic unchanged), the
// prefetched 8-deep gather loop is kept, and all combines are intra-block
// LDS (strip add for the token sum, float2 exchange for the matvec halves).
// ---------------------------------------------------------------------------
__global__ __launch_bounds__(256, 8) void fused_dan_kernel(
    const int* __restrict__ tok, const float* __restrict__ emb,
    const int* __restrict__ starts, const float* __restrict__ Wh,
    const float* __restrict__ bh, const float* __restrict__ Wo,
    const float* __restrict__ bo, const float* __restrict__ y,
    float* __restrict__ out, int Bval) {
    __shared__ float strip[4][HDIM];   // per-wave partial token-sum
    __shared__ float meanb[2][HDIM];   // per-segment mean (bias not applied)
    __shared__ float2 pm[2][64];       // sub==1 wave's K-half matvec partial
    __shared__ float lred[2];

    int wave = threadIdx.x >> 6;       // 0..3
    int lane = threadIdx.x & 63;
    int segb = wave >> 1;              // which of the block's 2 segments
    int sub  = wave & 1;               // half index (gather half & K half)
    int s = blockIdx.x * 2 + segb;
    bool valid = (s < Bval);

    float inv = 0.0f;
    int hw = lane >> 5, col = lane & 31;

    if (valid) {
        int t0 = starts[s];
        int t1 = starts[s + 1];
        int cnt = t1 - t0;
        inv = 1.0f / (float)(cnt > 0 ? cnt : 1);

        int halfTok = (cnt + 1) >> 1;
        int g0 = t0 + sub * halfTok;          // this wave's contiguous range
        int g1 = sub ? t1 : (t0 + halfTok);

        float4 acc = make_float4(0.f, 0.f, 0.f, 0.f);
        int i = g0 + hw;                      // half-wave stream, stride 2

        // prologue: prefetch first batch of token ids
        int tix[8];
        if (i + 14 < g1) {
            #pragma unroll
            for (int k = 0; k < 8; ++k) tix[k] = tok[i + 2 * k];
        }
        // main loop: 8 rows in flight per half-wave, tok ids one iter ahead
        while (i + 14 < g1) {
            float4 f[8];
            #pragma unroll
            for (int k = 0; k < 8; ++k)
                f[k] = ((const float4*)(emb + (size_t)tix[k] * HDIM))[col];
            int ni = i + 16;
            int ntix[8];
            if (ni + 14 < g1) {
                #pragma unroll
                for (int k = 0; k < 8; ++k) ntix[k] = tok[ni + 2 * k];
            }
            __builtin_amdgcn_sched_barrier(0);
            #pragma unroll
            for (int k = 0; k < 8; ++k) {
                acc.x += f[k].x; acc.y += f[k].y;
                acc.z += f[k].z; acc.w += f[k].w;
            }
            #pragma unroll
            for (int k = 0; k < 8; ++k) tix[k] = ntix[k];
            i = ni;
        }
        // masked epilogue: one clamped 8-deep pass covers the tail
        if (i < g1) {
            int lim = g1 - 1;
            int tix2[8]; float msk[8];
            #pragma unroll
            for (int k = 0; k < 8; ++k) {
                int ii = i + 2 * k;
                tix2[k] = tok[ii < lim ? ii : lim];
                msk[k] = (ii < g1) ? 1.0f : 0.0f;
            }
            float4 f[8];
            #pragma unroll
            for (int k = 0; k < 8; ++k)
                f[k] = ((const float4*)(emb + (size_t)tix2[k] * HDIM))[col];
            #pragma unroll
            for (int k = 0; k < 8; ++k) {
                acc.x = fmaf(f[k].x, msk[k], acc.x);
                acc.y = fmaf(f[k].y, msk[k], acc.y);
                acc.z = fmaf(f[k].z, msk[k], acc.z);
                acc.w = fmaf(f[k].w, msk[k], acc.w);
            }
        }

        // combine the two half-wave partials (lane l += lane l+32)
        acc.x += __shfl_down(acc.x, 32);
        acc.y += __shfl_down(acc.y, 32);
        acc.z += __shfl_down(acc.z, 32);
        acc.w += __shfl_down(acc.w, 32);
        if (hw == 0)
            ((float4*)&strip[wave][0])[col] = acc;
    }
    __syncthreads();   // strips of both waves of each pair visible

    float pa0 = 0.0f, pa1 = 0.0f;
    if (valid) {
        int w0 = segb * 2;
        int idx = sub * 64 + lane;             // the K row this lane owns
        float mv = (strip[w0][idx] + strip[w0 + 1][idx]) * inv;
        meanb[segb][idx] = mv;                 // same-wave RAW for own K half

        // matvec over this wave's K half; lane owns output cols 2l, 2l+1
        const float2* W2 = (const float2*)Wh;
        int ib = sub * 64;
        #pragma unroll 8
        for (int q = 0; q < 64; ++q) {
            float sv = meanb[segb][ib + q];    // uniform LDS read (broadcast)
            float2 w = W2[(size_t)(ib + q) * (HDIM / 2) + lane];
            pa0 = fmaf(sv, w.x, pa0);
            pa1 = fmaf(sv, w.y, pa1);
        }
        if (sub == 1) pm[segb][lane] = make_float2(pa0, pa1);
    }
    __syncthreads();   // K-half partials visible

    float lsum = 0.0f;
    if (valid && sub == 0) {
        float2 pp = pm[segb][lane];
        float2 bh2 = ((const float2*)bh)[lane];
        float2 wo2 = ((const float2*)Wo)[lane];
        float h0 = tanhf(pa0 + pp.x + bh2.x);
        float h1 = tanhf(pa1 + pp.y + bh2.y);
        float pr = h0 * wo2.x + h1 * wo2.y;
        #pragma unroll
        for (int mm = 1; mm < 64; mm <<= 1) pr += __shfl_xor(pr, mm);
        if (lane == 0) {
            float z = pr + bo[0];
            float p = 1.0f / (1.0f + expf(-z));
            float lp  = fmaxf(logf(p),    -100.0f);
            float l1p = fmaxf(log1pf(-p), -100.0f);
            float yv = y[s];
            lsum = -(yv * lp + (1.0f - yv) * l1p);
        }
    }

    if (sub == 0 && lane == 0) lred[segb] = lsum;   // 0 for invalid segments
    __syncthreads();
    if (threadIdx.x == 0)
        atomicAdd(out, lred[0] + lred[1]);
}

// ---------------------------------------------------------------------------
extern "C" void kernel_launch(void* const* d_in, const int* in_sizes, int n_in,
                              void* d_out, int out_size, void* d_ws, size_t ws_size,
                              hipStream_t stream) {
    const int*   tok = (const int*)d_in[0];
    const int*   seg = (const int*)d_in[1];
    const float* y   = (const float*)d_in[2];
    const float* emb = (const float*)d_in[3];
    const float* Wh  = (const float*)d_in[4];
    const float* bh  = (const float*)d_in[5];
    const float* Wo  = (const float*)d_in[6];
    const float* bo  = (const float*)d_in[7];

    int T_ = in_sizes[0];
    int B_ = in_sizes[2];

    float* out = (float*)d_out;
    int* starts = (int*)d_ws;   // only B+1 ints of workspace needed

    seg_bounds_kernel<<<(T_ + 255) / 256, 256, 0, stream>>>(seg, starts, T_, B_, out);
    fused_dan_kernel<<<(B_ + 1) / 2, 256, 0, stream>>>(tok, emb, starts, Wh, bh, Wo,
                                                       bo, y, out, B_);
}

// Round 5
// 129.746 us; speedup vs baseline: 1.0604x; 1.0604x over previous
//
#include <hip/hip_runtime.h>
#include <math.h>

#define HDIM 128

// ---------------------------------------------------------------------------
// Fused bounds + init + out-zero. segment_ids is sorted; starts[s] = first t
// with seg[t] >= s. Thread t covers (seg[t-1], seg[t]]; thread 0 covers
// [0, seg[0]]; thread T-1 covers trailing empty segments (seg[T-1], B] with T.
// ---------------------------------------------------------------------------
__global__ void seg_bounds_kernel(const int* __restrict__ seg,
                                  int* __restrict__ starts, int Tval, int Bval,
                                  float* __restrict__ out) {
    int t = blockIdx.x * blockDim.x + threadIdx.x;
    if (t >= Tval) return;
    int b = seg[t];
    int a = (t == 0) ? -1 : seg[t - 1];
    for (int s = a + 1; s <= b; ++s) starts[s] = t;
    if (t == Tval - 1)
        for (int s = b + 1; s <= Bval; ++s) starts[s] = Tval;
    if (t == 0) out[0] = 0.0f;
}

// ---------------------------------------------------------------------------
// Fused gather-mean + MLP + BCE.
// Gather (R3 structure — best measured): ONE wave per segment, 4 waves/block,
// 1024 blocks. R1-R4 showed the gather pinned at ~4.5 TB/s CU-side for any
// wave count / unroll depth (per-CU outstanding-miss limit x L2-miss
// latency); structure kept, no further gather tuning.
// MLP (new): block-batched. After the 4 means are in LDS, the 4 waves
// K-split the 128 rows of W_hid (32 rows each, 16 KB instead of 64 KB per
// wave - 4x less L2 traffic, ~4x shorter tail) and each computes partials
// for ALL 4 segments (means read as free LDS broadcasts). Partials combine
// through an 8 KB LDS exchange; wave w finishes its own segment s with
// bias + tanh + Wo-dot (shfl_xor) + BCE; one atomicAdd per block.
// ---------------------------------------------------------------------------
__global__ __launch_bounds__(256, 4) void fused_dan_kernel(
    const int* __restrict__ tok, const float* __restrict__ emb,
    const int* __restrict__ starts, const float* __restrict__ Wh,
    const float* __restrict__ bh, const float* __restrict__ Wo,
    const float* __restrict__ bo, const float* __restrict__ y,
    float* __restrict__ out, int Bval) {
    __shared__ float slds[4][HDIM];     // per-wave segment mean
    __shared__ float2 pm[4][4][64];     // [k-wave][segment][lane] partials
    __shared__ float lred[4];

    int wave = threadIdx.x >> 6;
    int lane = threadIdx.x & 63;
    int s = blockIdx.x * 4 + wave;
    bool valid = (s < Bval);

    if (valid) {
        int t0 = starts[s];
        int t1 = starts[s + 1];
        int cnt = t1 - t0;
        int half = lane >> 5;   // which token of the pair
        int col  = lane & 31;   // float4 column within the 128-float row

        float4 acc = make_float4(0.f, 0.f, 0.f, 0.f);
        int i = t0 + half;      // this half-wave's token stream (stride 2)

        // prologue: prefetch first batch of token ids
        int tix[8];
        if (i + 14 < t1) {
            #pragma unroll
            for (int k = 0; k < 8; ++k) tix[k] = tok[i + 2 * k];
        }
        // main loop: 8 rows per half-wave per iter, tok ids one iter ahead
        while (i + 14 < t1) {
            float4 f[8];
            #pragma unroll
            for (int k = 0; k < 8; ++k)
                f[k] = ((const float4*)(emb + (size_t)tix[k] * HDIM))[col];
            int ni = i + 16;
            int ntix[8];
            if (ni + 14 < t1) {
                #pragma unroll
                for (int k = 0; k < 8; ++k) ntix[k] = tok[ni + 2 * k];
            }
            __builtin_amdgcn_sched_barrier(0);
            #pragma unroll
            for (int k = 0; k < 8; ++k) {
                acc.x += f[k].x; acc.y += f[k].y;
                acc.z += f[k].z; acc.w += f[k].w;
            }
            #pragma unroll
            for (int k = 0; k < 8; ++k) tix[k] = ntix[k];
            i = ni;
        }
        // masked epilogue: one clamped 8-deep pass covers the tail
        if (i < t1) {
            int lim = t1 - 1;
            int tix2[8]; float msk[8];
            #pragma unroll
            for (int k = 0; k < 8; ++k) {
                int ii = i + 2 * k;
                tix2[k] = tok[ii < lim ? ii : lim];
                msk[k] = (ii < t1) ? 1.0f : 0.0f;
            }
            float4 f[8];
            #pragma unroll
            for (int k = 0; k < 8; ++k)
                f[k] = ((const float4*)(emb + (size_t)tix2[k] * HDIM))[col];
            #pragma unroll
            for (int k = 0; k < 8; ++k) {
                acc.x = fmaf(f[k].x, msk[k], acc.x);
                acc.y = fmaf(f[k].y, msk[k], acc.y);
                acc.z = fmaf(f[k].z, msk[k], acc.z);
                acc.w = fmaf(f[k].w, msk[k], acc.w);
            }
        }

        // combine the two half-wave partial sums (lane l += lane l+32)
        acc.x += __shfl_down(acc.x, 32);
        acc.y += __shfl_down(acc.y, 32);
        acc.z += __shfl_down(acc.z, 32);
        acc.w += __shfl_down(acc.w, 32);

        if (half == 0) {
            float inv = 1.0f / (float)(cnt > 0 ? cnt : 1);
            acc.x *= inv; acc.y *= inv; acc.z *= inv; acc.w *= inv;
            ((float4*)&slds[wave][0])[col] = acc;
        }
    } else {
        // zero the strip so the batched matvec reads defined values
        if (lane < 32)
            ((float4*)&slds[wave][0])[lane] = make_float4(0.f, 0.f, 0.f, 0.f);
    }
    __syncthreads();   // all 4 means visible

    // batched K-split matvec: this wave owns W rows [32*wave, 32*wave+32),
    // computes partials for all 4 segments. Lane owns output cols 2l, 2l+1.
    {
        const float2* W2 = (const float2*)Wh;
        float2 p0 = make_float2(0.f, 0.f), p1 = p0, p2 = p0, p3 = p0;
        int qb = wave * 32;
        #pragma unroll 4
        for (int q = 0; q < 32; ++q) {
            int row = qb + q;
            float2 w = W2[(size_t)row * (HDIM / 2) + lane];
            float s0 = slds[0][row];   // LDS broadcast (free)
            float s1 = slds[1][row];
            float s2 = slds[2][row];
            float s3 = slds[3][row];
            p0.x = fmaf(s0, w.x, p0.x); p0.y = fmaf(s0, w.y, p0.y);
            p1.x = fmaf(s1, w.x, p1.x); p1.y = fmaf(s1, w.y, p1.y);
            p2.x = fmaf(s2, w.x, p2.x); p2.y = fmaf(s2, w.y, p2.y);
            p3.x = fmaf(s3, w.x, p3.x); p3.y = fmaf(s3, w.y, p3.y);
        }
        pm[wave][0][lane] = p0;
        pm[wave][1][lane] = p1;
        pm[wave][2][lane] = p2;
        pm[wave][3][lane] = p3;
    }
    __syncthreads();   // all K partials visible

    float lsum = 0.0f;
    if (valid) {
        float2 q0 = pm[0][wave][lane];
        float2 q1 = pm[1][wave][lane];
        float2 q2 = pm[2][wave][lane];
        float2 q3 = pm[3][wave][lane];
        float2 bh2 = ((const float2*)bh)[lane];
        float2 wo2 = ((const float2*)Wo)[lane];
        float a0 = q0.x + q1.x + q2.x + q3.x + bh2.x;
        float a1 = q0.y + q1.y + q2.y + q3.y + bh2.y;
        float pr = tanhf(a0) * wo2.x + tanhf(a1) * wo2.y;
        #pragma unroll
        for (int mm = 1; mm < 64; mm <<= 1) pr += __shfl_xor(pr, mm);
        if (lane == 0) {
            float z = pr + bo[0];
            float p = 1.0f / (1.0f + expf(-z));
            float lp  = fmaxf(logf(p),    -100.0f);
            float l1p = fmaxf(log1pf(-p), -100.0f);
            float yv = y[s];
            lsum = -(yv * lp + (1.0f - yv) * l1p);
        }
    }

    if (lane == 0) lred[wave] = lsum;   // 0 for invalid segments
    __syncthreads();
    if (threadIdx.x == 0)
        atomicAdd(out, lred[0] + lred[1] + lred[2] + lred[3]);
}

// ---------------------------------------------------------------------------
extern "C" void kernel_launch(void* const* d_in, const int* in_sizes, int n_in,
                              void* d_out, int out_size, void* d_ws, size_t ws_size,
                              hipStream_t stream) {
    const int*   tok = (const int*)d_in[0];
    const int*   seg = (const int*)d_in[1];
    const float* y   = (const float*)d_in[2];
    const float* emb = (const float*)d_in[3];
    const float* Wh  = (const float*)d_in[4];
    const float* bh  = (const float*)d_in[5];
    const float* Wo  = (const float*)d_in[6];
    const float* bo  = (const float*)d_in[7];

    int T_ = in_sizes[0];
    int B_ = in_sizes[2];

    float* out = (float*)d_out;
    int* starts = (int*)d_ws;   // only B+1 ints of workspace needed

    seg_bounds_kernel<<<(T_ + 255) / 256, 256, 0, stream>>>(seg, starts, T_, B_, out);
    fused_dan_kernel<<<(B_ + 3) / 4, 256, 0, stream>>>(tok, emb, starts, Wh, bh, Wo,
                                                       bo, y, out, B_);
}

// Round 6
// 128.261 us; speedup vs baseline: 1.0727x; 1.0116x over previous
//
#include <hip/hip_runtime.h>
#include <math.h>

#define HDIM 128

// ---------------------------------------------------------------------------
// Fused bounds + init + out-zero. segment_ids is sorted; starts[s] = first t
// with seg[t] >= s. Thread t covers (seg[t-1], seg[t]]; thread 0 covers
// [0, seg[0]]; thread T-1 covers trailing empty segments (seg[T-1], B] with T.
// ---------------------------------------------------------------------------
__global__ void seg_bounds_kernel(const int* __restrict__ seg,
                                  int* __restrict__ starts, int Tval, int Bval,
                                  float* __restrict__ out) {
    int t = blockIdx.x * blockDim.x + threadIdx.x;
    if (t >= Tval) return;
    int b = seg[t];
    int a = (t == 0) ? -1 : seg[t - 1];
    for (int s = a + 1; s <= b; ++s) starts[s] = t;
    if (t == Tval - 1)
        for (int s = b + 1; s <= Bval; ++s) starts[s] = Tval;
    if (t == 0) out[0] = 0.0f;
}

// ---------------------------------------------------------------------------
// Fused gather-mean + MLP + BCE. R5 structure (best measured) with ONE
// change: the gather loop body is now a SINGLE basic block. Every prior
// round showed VGPR=32 => the compiler serialized the "8-deep" loads
// (8 live float4 alone need 32 VGPRs). Suspected cause: the conditional
// token-prefetch branch split the body; sched_barrier(0) in the merge
// block never constrained the load->use distance. Now: unconditional
// CLAMPED prefetch (min(ii, t1-1), always in-bounds), 8 named float4
// destinations, sched_barrier(0) between the load block and the add
// block. If VGPR jumps to ~80-96 and time drops, depth was the limiter;
// if time stays ~43 us, the per-CU MSHR wall is confirmed.
// MLP: block-batched 4-segment K-split matvec (R5, kept).
// ---------------------------------------------------------------------------
__global__ __launch_bounds__(256, 4) void fused_dan_kernel(
    const int* __restrict__ tok, const float* __restrict__ emb,
    const int* __restrict__ starts, const float* __restrict__ Wh,
    const float* __restrict__ bh, const float* __restrict__ Wo,
    const float* __restrict__ bo, const float* __restrict__ y,
    float* __restrict__ out, int Bval) {
    __shared__ float slds[4][HDIM];     // per-wave segment mean
    __shared__ float2 pm[4][4][64];     // [k-wave][segment][lane] partials
    __shared__ float lred[4];

    int wave = threadIdx.x >> 6;
    int lane = threadIdx.x & 63;
    int s = blockIdx.x * 4 + wave;
    bool valid = (s < Bval);

    if (valid) {
        int t0 = starts[s];
        int t1 = starts[s + 1];
        int cnt = t1 - t0;
        int half = lane >> 5;   // which token of the pair
        int col  = lane & 31;   // float4 column within the 128-float row
        int lim  = t1 - 1;      // clamp target for prefetch

        float4 acc = make_float4(0.f, 0.f, 0.f, 0.f);
        int i = t0 + half;      // this half-wave's token stream (stride 2)

        // prologue: clamped prefetch of first token batch (safe even if
        // the main loop is never entered; values then unused)
        int x0, x1, x2, x3, x4, x5, x6, x7;
        {
            int i0 = i;
            x0 = tok[i0      < lim ? i0      : lim];
            x1 = tok[i0 + 2  < lim ? i0 + 2  : lim];
            x2 = tok[i0 + 4  < lim ? i0 + 4  : lim];
            x3 = tok[i0 + 6  < lim ? i0 + 6  : lim];
            x4 = tok[i0 + 8  < lim ? i0 + 8  : lim];
            x5 = tok[i0 + 10 < lim ? i0 + 10 : lim];
            x6 = tok[i0 + 12 < lim ? i0 + 12 : lim];
            x7 = tok[i0 + 14 < lim ? i0 + 14 : lim];
        }

        // main loop: straight-line single-BB body; 8 named rows in flight
        while (i + 14 < t1) {
            const float4* r0 = (const float4*)(emb + (size_t)x0 * HDIM);
            const float4* r1 = (const float4*)(emb + (size_t)x1 * HDIM);
            const float4* r2 = (const float4*)(emb + (size_t)x2 * HDIM);
            const float4* r3 = (const float4*)(emb + (size_t)x3 * HDIM);
            const float4* r4 = (const float4*)(emb + (size_t)x4 * HDIM);
            const float4* r5 = (const float4*)(emb + (size_t)x5 * HDIM);
            const float4* r6 = (const float4*)(emb + (size_t)x6 * HDIM);
            const float4* r7 = (const float4*)(emb + (size_t)x7 * HDIM);
            float4 f0 = r0[col], f1 = r1[col], f2 = r2[col], f3 = r3[col];
            float4 f4 = r4[col], f5 = r5[col], f6 = r6[col], f7 = r7[col];

            int ni = i + 16;    // unconditional clamped prefetch (no branch)
            int n0 = ni      < lim ? ni      : lim;
            int n1 = ni + 2  < lim ? ni + 2  : lim;
            int n2 = ni + 4  < lim ? ni + 4  : lim;
            int n3 = ni + 6  < lim ? ni + 6  : lim;
            int n4 = ni + 8  < lim ? ni + 8  : lim;
            int n5 = ni + 10 < lim ? ni + 10 : lim;
            int n6 = ni + 12 < lim ? ni + 12 : lim;
            int n7 = ni + 14 < lim ? ni + 14 : lim;
            x0 = tok[n0]; x1 = tok[n1]; x2 = tok[n2]; x3 = tok[n3];
            x4 = tok[n4]; x5 = tok[n5]; x6 = tok[n6]; x7 = tok[n7];

            // nothing may cross: all 16 loads issued before any add
            __builtin_amdgcn_sched_barrier(0);

            acc.x += f0.x + f1.x + f2.x + f3.x + f4.x + f5.x + f6.x + f7.x;
            acc.y += f0.y + f1.y + f2.y + f3.y + f4.y + f5.y + f6.y + f7.y;
            acc.z += f0.z + f1.z + f2.z + f3.z + f4.z + f5.z + f6.z + f7.z;
            acc.w += f0.w + f1.w + f2.w + f3.w + f4.w + f5.w + f6.w + f7.w;
            i = ni;
        }

        // masked epilogue: one clamped 8-deep pass covers the tail
        if (i < t1) {
            int tix2[8]; float msk[8];
            #pragma unroll
            for (int k = 0; k < 8; ++k) {
                int ii = i + 2 * k;
                tix2[k] = tok[ii < lim ? ii : lim];
                msk[k] = (ii < t1) ? 1.0f : 0.0f;
            }
            float4 f[8];
            #pragma unroll
            for (int k = 0; k < 8; ++k)
                f[k] = ((const float4*)(emb + (size_t)tix2[k] * HDIM))[col];
            #pragma unroll
            for (int k = 0; k < 8; ++k) {
                acc.x = fmaf(f[k].x, msk[k], acc.x);
                acc.y = fmaf(f[k].y, msk[k], acc.y);
                acc.z = fmaf(f[k].z, msk[k], acc.z);
                acc.w = fmaf(f[k].w, msk[k], acc.w);
            }
        }

        // combine the two half-wave partial sums (lane l += lane l+32)
        acc.x += __shfl_down(acc.x, 32);
        acc.y += __shfl_down(acc.y, 32);
        acc.z += __shfl_down(acc.z, 32);
        acc.w += __shfl_down(acc.w, 32);

        if (half == 0) {
            float inv = 1.0f / (float)(cnt > 0 ? cnt : 1);
            acc.x *= inv; acc.y *= inv; acc.z *= inv; acc.w *= inv;
            ((float4*)&slds[wave][0])[col] = acc;
        }
    } else {
        // zero the strip so the batched matvec reads defined values
        if (lane < 32)
            ((float4*)&slds[wave][0])[lane] = make_float4(0.f, 0.f, 0.f, 0.f);
    }
    __syncthreads();   // all 4 means visible

    // batched K-split matvec: this wave owns W rows [32*wave, 32*wave+32),
    // computes partials for all 4 segments. Lane owns output cols 2l, 2l+1.
    {
        const float2* W2 = (const float2*)Wh;
        float2 p0 = make_float2(0.f, 0.f), p1 = p0, p2 = p0, p3 = p0;
        int qb = wave * 32;
        #pragma unroll 4
        for (int q = 0; q < 32; ++q) {
            int row = qb + q;
            float2 w = W2[(size_t)row * (HDIM / 2) + lane];
            float s0 = slds[0][row];   // LDS broadcast (free)
            float s1 = slds[1][row];
            float s2 = slds[2][row];
            float s3 = slds[3][row];
            p0.x = fmaf(s0, w.x, p0.x); p0.y = fmaf(s0, w.y, p0.y);
            p1.x = fmaf(s1, w.x, p1.x); p1.y = fmaf(s1, w.y, p1.y);
            p2.x = fmaf(s2, w.x, p2.x); p2.y = fmaf(s2, w.y, p2.y);
            p3.x = fmaf(s3, w.x, p3.x); p3.y = fmaf(s3, w.y, p3.y);
        }
        pm[wave][0][lane] = p0;
        pm[wave][1][lane] = p1;
        pm[wave][2][lane] = p2;
        pm[wave][3][lane] = p3;
    }
    __syncthreads();   // all K partials visible

    float lsum = 0.0f;
    if (valid) {
        float2 q0 = pm[0][wave][lane];
        float2 q1 = pm[1][wave][lane];
        float2 q2 = pm[2][wave][lane];
        float2 q3 = pm[3][wave][lane];
        float2 bh2 = ((const float2*)bh)[lane];
        float2 wo2 = ((const float2*)Wo)[lane];
        float a0 = q0.x + q1.x + q2.x + q3.x + bh2.x;
        float a1 = q0.y + q1.y + q2.y + q3.y + bh2.y;
        float pr = tanhf(a0) * wo2.x + tanhf(a1) * wo2.y;
        #pragma unroll
        for (int mm = 1; mm < 64; mm <<= 1) pr += __shfl_xor(pr, mm);
        if (lane == 0) {
            float z = pr + bo[0];
            float p = 1.0f / (1.0f + expf(-z));
            float lp  = fmaxf(logf(p),    -100.0f);
            float l1p = fmaxf(log1pf(-p), -100.0f);
            float yv = y[s];
            lsum = -(yv * lp + (1.0f - yv) * l1p);
        }
    }

    if (lane == 0) lred[wave] = lsum;   // 0 for invalid segments
    __syncthreads();
    if (threadIdx.x == 0)
        atomicAdd(out, lred[0] + lred[1] + lred[2] + lred[3]);
}

// ---------------------------------------------------------------------------
extern "C" void kernel_launch(void* const* d_in, const int* in_sizes, int n_in,
                              void* d_out, int out_size, void* d_ws, size_t ws_size,
                              hipStream_t stream) {
    const int*   tok = (const int*)d_in[0];
    const int*   seg = (const int*)d_in[1];
    const float* y   = (const float*)d_in[2];
    const float* emb = (const float*)d_in[3];
    const float* Wh  = (const float*)d_in[4];
    const float* bh  = (const float*)d_in[5];
    const float* Wo  = (const float*)d_in[6];
    const float* bo  = (const float*)d_in[7];

    int T_ = in_sizes[0];
    int B_ = in_sizes[2];

    float* out = (float*)d_out;
    int* starts = (int*)d_ws;   // only B+1 ints of workspace needed

    seg_bounds_kernel<<<(T_ + 255) / 256, 256, 0, stream>>>(seg, starts, T_, B_, out);
    fused_dan_kernel<<<(B_ + 3) / 4, 256, 0, stream>>>(tok, emb, starts, Wh, bh, Wo,
                                                       bo, y, out, B_);
}